// Round 8
// baseline (962.493 us; speedup 1.0000x reference)
//
#include <hip/hip_runtime.h>
#include <math.h>

typedef short short8 __attribute__((ext_vector_type(8)));
typedef float f32x4 __attribute__((ext_vector_type(4)));

#define MAXDEG 32
#define GF_BIAS   1
#define GF_CSHIFT 2
#define GF_ALPHA  4
#define NFRAG 18432   // 9 nt-tiles * 4 kt * 64 lanes * 8 bf16

__device__ __forceinline__ unsigned short f2bf(float f) {  // RNE f32->bf16
  unsigned u = __float_as_uint(f);
  u += 0x7FFF + ((u >> 16) & 1);
  return (unsigned short)(u >> 16);
}
__device__ __forceinline__ float bf2f(unsigned short s) { return __uint_as_float(((unsigned)s) << 16); }
__device__ __forceinline__ float lrelu(float v) { return v > 0.f ? v : 0.2f * v; }

// ---------------- CSR slot-scatter (3 relations) + fused geo reduce ----------------
__global__ __launch_bounds__(256) void k_scatter3(
    const int* __restrict__ ei0, const int* __restrict__ ei1, const int* __restrict__ ei2,
    int* __restrict__ cur,
    int* __restrict__ s0, int* __restrict__ s1, int* __restrict__ s2,
    const float* __restrict__ pos, float* __restrict__ gsum, int E, int N) {
  __shared__ float part[4];
  const int T4 = gridDim.x * 256;
  const int t = blockIdx.x * 256 + threadIdx.x;
  float d = 0.f;
  #pragma unroll
  for (int k = 0; k < 4; ++k) {
    const int idx = t + k * T4;
    if (idx >= 3 * E) continue;
    int rel, e;
    if (idx < E)          { rel = 0; e = idx; }
    else if (idx < 2 * E) { rel = 1; e = idx - E; }
    else                  { rel = 2; e = idx - 2 * E; }
    const int* ei = (rel == 0) ? ei0 : (rel == 1) ? ei1 : ei2;
    int* srcs     = (rel == 0) ? s0  : (rel == 1) ? s1  : s2;
    const int r = ei[e];
    const int c = ei[E + e];
    const int slot = atomicAdd(&cur[rel * N + c], 1);
    if (slot < MAXDEG) srcs[(size_t)c * MAXDEG + slot] = r;
    if (rel == 2) {
      const float dx = pos[3*r]   - pos[3*c];
      const float dy = pos[3*r+1] - pos[3*c+1];
      const float dz = pos[3*r+2] - pos[3*c+2];
      d += sqrtf(dx*dx + dy*dy + dz*dz);
    }
  }
  #pragma unroll
  for (int o = 32; o; o >>= 1) d += __shfl_down(d, o);
  if ((threadIdx.x & 63) == 0) part[threadIdx.x >> 6] = d;
  __syncthreads();
  if (threadIdx.x == 0) {
    const float s = part[0] + part[1] + part[2] + part[3];
    if (s != 0.f) atomicAdd(gsum, s);
  }
}

// ---------------- weight prep: bf16 hi/lo fragment images + alpha cols + colsums ----
struct PrepArgs {
  const float* W[9];
  const float* as_[9];
  const float* ad_[9];
  unsigned short* hi[9];
  unsigned short* lo[9];
  float* csum[9];
  int fh[9];   // 0 = no alpha cols
};

__global__ __launch_bounds__(256) void k_prep(PrepArgs p) {
  const int s = blockIdx.x;
  const int t = threadIdx.x;
  const float* W = p.W[s];
  const int fh = p.fh[s];
  __shared__ float Ws[128 * 129];
  __shared__ float alpha[128 * 8];
  {
    const f32x4* src = (const f32x4*)W;
    for (int i = t; i < 4096; i += 256) {     // 16384 floats, coalesced
      const f32x4 v = src[i];
      const int row = i >> 5;
      const int col = (i & 31) * 4;
      float* dst = &Ws[row * 129 + col];
      dst[0] = v[0]; dst[1] = v[1]; dst[2] = v[2]; dst[3] = v[3];
    }
  }
  __syncthreads();
  if (t < 128) {
    #pragma unroll
    for (int a = 0; a < 8; ++a) alpha[t * 8 + a] = 0.f;
    if (fh) {
      const int nh = 128 / fh;
      for (int h = 0; h < nh; ++h) {
        float s1 = 0.f, s2 = 0.f;
        for (int c = 0; c < fh; ++c) {
          const float w = Ws[t * 129 + h * fh + c];
          s1 += w * p.as_[s][h * fh + c];
          s2 += w * p.ad_[s][h * fh + c];
        }
        alpha[t * 8 + h] = s1;
        alpha[t * 8 + 4 + h] = s2;
      }
    }
  }
  __syncthreads();
  for (int idx = t; idx < NFRAG; idx += 256) {
    const int j = idx & 7, lane = (idx >> 3) & 63, kt = (idx >> 9) & 3, nt = idx >> 11;
    const int k = kt * 32 + (lane >> 4) * 8 + j;
    const int col = nt * 16 + (lane & 15);
    float w;
    if (col < 128) w = Ws[k * 129 + col];
    else if (col < 136) w = alpha[k * 8 + (col - 128)];
    else w = 0.f;
    const unsigned short h = f2bf(w);
    p.hi[s][idx] = h;
    p.lo[s][idx] = f2bf(w - bf2f(h));
  }
  if (t < 136) {
    float cs = 0.f;
    if (t < 128) for (int k = 0; k < 128; ++k) cs += Ws[k * 129 + t];
    else         for (int k = 0; k < 128; ++k) cs += alpha[k * 8 + (t - 128)];
    p.csum[s][t] = cs;
  }
}

// ---------------- split-bf16 MFMA GEMM, LDS-free: B fragments straight from L2 -----
// Weight images are 72 KB and L2-hot; per-wave fragment reads are 64x16B coalesced.
// No staging, no barriers, no LDS occupancy cap (was 2 blocks/CU; now VGPR-bound).
__global__ __launch_bounds__(256) void k_gmm(
    const float* __restrict__ A, const unsigned short* __restrict__ Whi,
    const unsigned short* __restrict__ Wlo, const float* __restrict__ csum,
    const float* __restrict__ bias, float* __restrict__ C,
    float* __restrict__ aS, float* __restrict__ aD,
    const float* __restrict__ gsum, float gscale,
    int n, int npad, int flags)
{
  const int wave = threadIdx.x >> 6, lane = threadIdx.x & 63;
  const int m = lane & 15, kq = lane >> 4;
  const float cb = (flags & GF_CSHIFT) ? gscale * gsum[0] : 0.f;

  for (int rb = blockIdx.x * 128; rb < npad; rb += gridDim.x * 128) {
    const int rw = rb + wave * 32;
    short8 ah[2][4], al[2][4];
    #pragma unroll
    for (int sub = 0; sub < 2; ++sub) {
      const int row = rw + sub * 16 + m;
      const bool ok = row < n;
      const float* ap = A + (size_t)row * 128 + kq * 8;
      #pragma unroll
      for (int kt = 0; kt < 4; ++kt) {
        f32x4 x0 = {0.f, 0.f, 0.f, 0.f}, x1 = {0.f, 0.f, 0.f, 0.f};
        if (ok) { x0 = *(const f32x4*)(ap + kt * 32); x1 = *(const f32x4*)(ap + kt * 32 + 4); }
        #pragma unroll
        for (int j = 0; j < 4; ++j) {
          unsigned short h0 = f2bf(x0[j]);
          ah[sub][kt][j] = (short)h0;
          al[sub][kt][j] = (short)f2bf(x0[j] - bf2f(h0));
          unsigned short h1 = f2bf(x1[j]);
          ah[sub][kt][4 + j] = (short)h1;
          al[sub][kt][4 + j] = (short)f2bf(x1[j] - bf2f(h1));
        }
      }
    }
    f32x4 acc[2][9];
    #pragma unroll
    for (int sub = 0; sub < 2; ++sub)
      #pragma unroll
      for (int nt = 0; nt < 9; ++nt) acc[sub][nt] = f32x4{0.f, 0.f, 0.f, 0.f};

    #pragma unroll
    for (int nt = 0; nt < 9; ++nt) {
      #pragma unroll
      for (int kt = 0; kt < 4; ++kt) {
        const int fo = ((nt * 4 + kt) * 64 + lane) * 8;
        const short8 bh = *(const short8*)&Whi[fo];
        const short8 bl = *(const short8*)&Wlo[fo];
        #pragma unroll
        for (int sub = 0; sub < 2; ++sub) {
          acc[sub][nt] = __builtin_amdgcn_mfma_f32_16x16x32_bf16(ah[sub][kt], bh, acc[sub][nt], 0, 0, 0);
          acc[sub][nt] = __builtin_amdgcn_mfma_f32_16x16x32_bf16(al[sub][kt], bh, acc[sub][nt], 0, 0, 0);
          acc[sub][nt] = __builtin_amdgcn_mfma_f32_16x16x32_bf16(ah[sub][kt], bl, acc[sub][nt], 0, 0, 0);
        }
      }
    }
    // epilogue: C/D layout col = lane&15, row = (lane>>4)*4 + r
    #pragma unroll
    for (int sub = 0; sub < 2; ++sub) {
      const int rbase = rw + sub * 16 + kq * 4;
      #pragma unroll
      for (int nt = 0; nt < 8; ++nt) {
        const int col = nt * 16 + m;
        const float cs = (flags & GF_CSHIFT) ? cb * csum[col] : 0.f;
        const float bb = (flags & GF_BIAS) ? bias[col] : 0.f;
        #pragma unroll
        for (int r = 0; r < 4; ++r)
          C[(size_t)(rbase + r) * 128 + col] = acc[sub][nt][r] + cs + bb;
      }
      if ((flags & GF_ALPHA) && m < 8) {
        const float cs = (flags & GF_CSHIFT) ? cb * csum[128 + m] : 0.f;
        #pragma unroll
        for (int r = 0; r < 4; ++r) {
          const float v = acc[sub][8][r] + cs;
          const int row = rbase + r;
          if (m < 4) aS[(size_t)row * 4 + m] = v;
          else       aD[(size_t)row * 4 + (m - 4)] = v;
        }
      }
    }
  }
}

// ---------------- fused 3-weight GEMM, LDS-free: A converted once, B from L2 -------
// set 0 = mol (cshift + alpha), set 1 = chem (alpha), set 2 = cond (alpha).
__global__ __launch_bounds__(256) void k_gmm3(
    const float* __restrict__ A,
    const unsigned short* __restrict__ hi0, const unsigned short* __restrict__ lo0,
    const unsigned short* __restrict__ hi1, const unsigned short* __restrict__ lo1,
    const unsigned short* __restrict__ hi2, const unsigned short* __restrict__ lo2,
    const float* __restrict__ csum0, const float* __restrict__ gsum, float gscale,
    float* __restrict__ C0, float* __restrict__ C1, float* __restrict__ C2,
    float* __restrict__ aS0, float* __restrict__ aD0,
    float* __restrict__ aS1, float* __restrict__ aD1,
    float* __restrict__ aS2, float* __restrict__ aD2,
    int n, int npad)
{
  const int wave = threadIdx.x >> 6, lane = threadIdx.x & 63;
  const int m = lane & 15, kq = lane >> 4;
  const float cb = gscale * gsum[0];

  for (int rb = blockIdx.x * 128; rb < npad; rb += gridDim.x * 128) {
    const int rw = rb + wave * 32;
    short8 ah[2][4], al[2][4];
    #pragma unroll
    for (int sub = 0; sub < 2; ++sub) {
      const int row = rw + sub * 16 + m;
      const bool ok = row < n;
      const float* ap = A + (size_t)row * 128 + kq * 8;
      #pragma unroll
      for (int kt = 0; kt < 4; ++kt) {
        f32x4 x0 = {0.f, 0.f, 0.f, 0.f}, x1 = {0.f, 0.f, 0.f, 0.f};
        if (ok) { x0 = *(const f32x4*)(ap + kt * 32); x1 = *(const f32x4*)(ap + kt * 32 + 4); }
        #pragma unroll
        for (int j = 0; j < 4; ++j) {
          unsigned short h0 = f2bf(x0[j]);
          ah[sub][kt][j] = (short)h0;
          al[sub][kt][j] = (short)f2bf(x0[j] - bf2f(h0));
          unsigned short h1 = f2bf(x1[j]);
          ah[sub][kt][4 + j] = (short)h1;
          al[sub][kt][4 + j] = (short)f2bf(x1[j] - bf2f(h1));
        }
      }
    }

    #pragma unroll
    for (int set = 0; set < 3; ++set) {
      const unsigned short* hi = (set == 0) ? hi0 : (set == 1) ? hi1 : hi2;
      const unsigned short* lo = (set == 0) ? lo0 : (set == 1) ? lo1 : lo2;

      f32x4 acc[2][9];
      #pragma unroll
      for (int sub = 0; sub < 2; ++sub)
        #pragma unroll
        for (int nt = 0; nt < 9; ++nt) acc[sub][nt] = f32x4{0.f, 0.f, 0.f, 0.f};

      #pragma unroll
      for (int nt = 0; nt < 9; ++nt) {
        #pragma unroll
        for (int kt = 0; kt < 4; ++kt) {
          const int fo = ((nt * 4 + kt) * 64 + lane) * 8;
          const short8 bh = *(const short8*)&hi[fo];
          const short8 bl = *(const short8*)&lo[fo];
          #pragma unroll
          for (int sub = 0; sub < 2; ++sub) {
            acc[sub][nt] = __builtin_amdgcn_mfma_f32_16x16x32_bf16(ah[sub][kt], bh, acc[sub][nt], 0, 0, 0);
            acc[sub][nt] = __builtin_amdgcn_mfma_f32_16x16x32_bf16(al[sub][kt], bh, acc[sub][nt], 0, 0, 0);
            acc[sub][nt] = __builtin_amdgcn_mfma_f32_16x16x32_bf16(ah[sub][kt], bl, acc[sub][nt], 0, 0, 0);
          }
        }
      }

      float* C  = (set == 0) ? C0  : (set == 1) ? C1  : C2;
      float* aS = (set == 0) ? aS0 : (set == 1) ? aS1 : aS2;
      float* aD = (set == 0) ? aD0 : (set == 1) ? aD1 : aD2;
      const float cbs = (set == 0) ? cb : 0.f;
      #pragma unroll
      for (int sub = 0; sub < 2; ++sub) {
        const int rbase = rw + sub * 16 + kq * 4;
        #pragma unroll
        for (int nt = 0; nt < 8; ++nt) {
          const int col = nt * 16 + m;
          const float cs = cbs * csum0[col];
          #pragma unroll
          for (int r = 0; r < 4; ++r)
            C[(size_t)(rbase + r) * 128 + col] = acc[sub][nt][r] + cs;
        }
        if (m < 8) {
          const float cs = cbs * csum0[128 + m];
          #pragma unroll
          for (int r = 0; r < 4; ++r) {
            const float v = acc[sub][8][r] + cs;
            const int row = rbase + r;
            if (m < 4) aS[(size_t)row * 4 + m] = v;
            else       aD[(size_t)row * 4 + (m - 4)] = v;
          }
        }
      }
    }
  }
}

// ---------------- GAT conv: 2 dst nodes per wave, 32 lanes each, float4/lane -------
// mode: 0 = write, 1 = accumulate, 2 = accumulate + relu
__global__ __launch_bounds__(256) void k_conv(
    const float* __restrict__ h, const float* __restrict__ aS, const float* __restrict__ aD,
    const int* __restrict__ srcs, const int* __restrict__ cnt,
    const float* __restrict__ bias, float* __restrict__ out,
    int fh_shift, int mode, int n)
{
  __shared__ int   ssh[4][2][32];
  __shared__ float wsh[4][2][32][4];
  const int wv = threadIdx.x >> 6;
  const int lane = threadIdx.x & 63;
  const int hf = lane >> 5;              // which node within the wave
  const int l  = lane & 31;
  const int i = blockIdx.x * 8 + wv * 2 + hf;
  const bool iok = i < n;
  const int ipad = iok ? i : 0;
  const int c0 = l * 4;
  const int hd = c0 >> fh_shift;

  int deg = 0;
  if (iok) { deg = cnt[i]; if (deg > MAXDEG) deg = MAXDEG; }
  const int* sp = srcs + (size_t)ipad * MAXDEG;

  const bool valid = l < deg;
  int s = ipad;
  if (valid) s = sp[l];

  f32x4 ad4 = f32x4{0.f, 0.f, 0.f, 0.f}, asi = f32x4{0.f, 0.f, 0.f, 0.f};
  if (iok) {
    ad4 = *(const f32x4*)(aD + (size_t)i * 4);
    asi = *(const f32x4*)(aS + (size_t)i * 4);
  }
  f32x4 as4 = f32x4{0.f, 0.f, 0.f, 0.f};
  if (valid) as4 = *(const f32x4*)(aS + (size_t)s * 4);

  f32x4 e, eself;
  #pragma unroll
  for (int hh = 0; hh < 4; ++hh) {
    e[hh] = lrelu(as4[hh] + ad4[hh]);
    eself[hh] = lrelu(asi[hh] + ad4[hh]);
  }

  f32x4 mx;
  #pragma unroll
  for (int hh = 0; hh < 4; ++hh) mx[hh] = valid ? e[hh] : -1e30f;
  #pragma unroll
  for (int o = 16; o; o >>= 1) {
    #pragma unroll
    for (int hh = 0; hh < 4; ++hh) mx[hh] = fmaxf(mx[hh], __shfl_xor(mx[hh], o, 32));
  }
  #pragma unroll
  for (int hh = 0; hh < 4; ++hh) mx[hh] = fmaxf(mx[hh], eself[hh]);

  f32x4 w, z;
  #pragma unroll
  for (int hh = 0; hh < 4; ++hh) { w[hh] = valid ? __expf(e[hh] - mx[hh]) : 0.f; z[hh] = w[hh]; }
  #pragma unroll
  for (int o = 16; o; o >>= 1) {
    #pragma unroll
    for (int hh = 0; hh < 4; ++hh) z[hh] += __shfl_xor(z[hh], o, 32);
  }
  f32x4 wsf;
  #pragma unroll
  for (int hh = 0; hh < 4; ++hh) { wsf[hh] = __expf(eself[hh] - mx[hh]); z[hh] += wsf[hh]; }

  int dtot = (deg + 3) & ~3;
  const int dmax = max(dtot, __shfl_xor(dtot, 32));
  if (l < dmax) {
    ssh[wv][hf][l] = valid ? s : ipad;
    f32x4 wst = f32x4{0.f, 0.f, 0.f, 0.f};
    if (valid) wst = w;
    *(f32x4*)wsh[wv][hf][l] = wst;
  }

  f32x4 acc = f32x4{0.f, 0.f, 0.f, 0.f};
  {
    f32x4 hvi = f32x4{0.f, 0.f, 0.f, 0.f};
    if (iok) hvi = *(const f32x4*)(h + (size_t)i * 128 + c0);
    const float ws = wsf[hd];
    #pragma unroll
    for (int q = 0; q < 4; ++q) acc[q] = ws * hvi[q];
  }
  for (int j0 = 0; j0 < dmax; j0 += 4) {
    const int s0 = ssh[wv][hf][j0],     s1 = ssh[wv][hf][j0 + 1];
    const int s2 = ssh[wv][hf][j0 + 2], s3 = ssh[wv][hf][j0 + 3];
    const float w0 = wsh[wv][hf][j0][hd],     w1 = wsh[wv][hf][j0 + 1][hd];
    const float w2 = wsh[wv][hf][j0 + 2][hd], w3 = wsh[wv][hf][j0 + 3][hd];
    const f32x4 v0 = *(const f32x4*)(h + (size_t)s0 * 128 + c0);
    const f32x4 v1 = *(const f32x4*)(h + (size_t)s1 * 128 + c0);
    const f32x4 v2 = *(const f32x4*)(h + (size_t)s2 * 128 + c0);
    const f32x4 v3 = *(const f32x4*)(h + (size_t)s3 * 128 + c0);
    #pragma unroll
    for (int q = 0; q < 4; ++q)
      acc[q] += w0 * v0[q] + w1 * v1[q] + w2 * v2[q] + w3 * v3[q];
  }

  if (!iok) return;
  const float inv = 1.f / (z[hd] + 1e-16f);
  const f32x4 bb = *(const f32x4*)(bias + c0);
  float* op = out + (size_t)i * 128 + c0;
  f32x4 res;
  #pragma unroll
  for (int q = 0; q < 4; ++q) res[q] = acc[q] * inv + bb[q];
  if (mode == 0) { *(f32x4*)op = res; }
  else {
    f32x4 cur = *(const f32x4*)op;
    #pragma unroll
    for (int q = 0; q < 4; ++q) {
      float r = cur[q] + res[q];
      if (mode == 2) r = fmaxf(r, 0.f);
      res[q] = r;
    }
    *(f32x4*)op = res;
  }
}

// ---------------- fused 2-relation GAT conv: out = relu(out + conv_c + conv_d) -----
__global__ __launch_bounds__(256) void k_conv2(
    const float* __restrict__ hcp, const float* __restrict__ hdp,
    const float* __restrict__ aSc, const float* __restrict__ aDc,
    const float* __restrict__ aSd, const float* __restrict__ aDd,
    const int* __restrict__ srcs_c, const int* __restrict__ cnt_c,
    const int* __restrict__ srcs_d, const int* __restrict__ cnt_d,
    const float* __restrict__ bias_c, const float* __restrict__ bias_d,
    float* __restrict__ out, int fh_shift, int n)
{
  __shared__ int   ssh[4][2][2][32];        // [wave][rel][half][slot]
  __shared__ float wsh[4][2][2][32][4];
  const int wv = threadIdx.x >> 6;
  const int lane = threadIdx.x & 63;
  const int hf = lane >> 5;
  const int l  = lane & 31;
  const int i = blockIdx.x * 8 + wv * 2 + hf;
  const bool iok = i < n;
  const int ipad = iok ? i : 0;
  const int c0 = l * 4;
  const int hd = c0 >> fh_shift;

  const float* hA[2]   = {hcp, hdp};
  const float* aSA[2]  = {aSc, aSd};
  const float* aDA[2]  = {aDc, aDd};
  const int*   spA[2]  = {srcs_c, srcs_d};
  const int*   cntA[2] = {cnt_c, cnt_d};

  f32x4 acc = f32x4{0.f, 0.f, 0.f, 0.f};

  #pragma unroll
  for (int rel = 0; rel < 2; ++rel) {
    int deg = 0;
    if (iok) { deg = cntA[rel][i]; if (deg > MAXDEG) deg = MAXDEG; }
    const int* sp = spA[rel] + (size_t)ipad * MAXDEG;

    const bool valid = l < deg;
    int s = ipad;
    if (valid) s = sp[l];

    f32x4 ad4 = f32x4{0.f, 0.f, 0.f, 0.f}, asi = f32x4{0.f, 0.f, 0.f, 0.f};
    if (iok) {
      ad4 = *(const f32x4*)(aDA[rel] + (size_t)i * 4);
      asi = *(const f32x4*)(aSA[rel] + (size_t)i * 4);
    }
    f32x4 as4 = f32x4{0.f, 0.f, 0.f, 0.f};
    if (valid) as4 = *(const f32x4*)(aSA[rel] + (size_t)s * 4);

    f32x4 e, eself;
    #pragma unroll
    for (int hh = 0; hh < 4; ++hh) {
      e[hh] = lrelu(as4[hh] + ad4[hh]);
      eself[hh] = lrelu(asi[hh] + ad4[hh]);
    }

    f32x4 mx;
    #pragma unroll
    for (int hh = 0; hh < 4; ++hh) mx[hh] = valid ? e[hh] : -1e30f;
    #pragma unroll
    for (int o = 16; o; o >>= 1) {
      #pragma unroll
      for (int hh = 0; hh < 4; ++hh) mx[hh] = fmaxf(mx[hh], __shfl_xor(mx[hh], o, 32));
    }
    #pragma unroll
    for (int hh = 0; hh < 4; ++hh) mx[hh] = fmaxf(mx[hh], eself[hh]);

    f32x4 w, z;
    #pragma unroll
    for (int hh = 0; hh < 4; ++hh) { w[hh] = valid ? __expf(e[hh] - mx[hh]) : 0.f; z[hh] = w[hh]; }
    #pragma unroll
    for (int o = 16; o; o >>= 1) {
      #pragma unroll
      for (int hh = 0; hh < 4; ++hh) z[hh] += __shfl_xor(z[hh], o, 32);
    }
    f32x4 wsf, inv;
    #pragma unroll
    for (int hh = 0; hh < 4; ++hh) {
      wsf[hh] = __expf(eself[hh] - mx[hh]);
      z[hh] += wsf[hh];
      inv[hh] = 1.f / (z[hh] + 1e-16f);
    }

    int dtot = (deg + 3) & ~3;
    const int dmax = max(dtot, __shfl_xor(dtot, 32));
    if (l < dmax) {
      ssh[wv][rel][hf][l] = valid ? s : ipad;
      f32x4 wst = f32x4{0.f, 0.f, 0.f, 0.f};
      if (valid) {
        #pragma unroll
        for (int hh = 0; hh < 4; ++hh) wst[hh] = w[hh] * inv[hh];
      }
      *(f32x4*)wsh[wv][rel][hf][l] = wst;
    }

    const float* hmat = hA[rel];
    // self row (normalized weight)
    {
      f32x4 hvi = f32x4{0.f, 0.f, 0.f, 0.f};
      if (iok) hvi = *(const f32x4*)(hmat + (size_t)i * 128 + c0);
      const float ws = wsf[hd] * inv[hd];
      #pragma unroll
      for (int q = 0; q < 4; ++q) acc[q] += ws * hvi[q];
    }
    for (int j0 = 0; j0 < dmax; j0 += 4) {
      const int s0 = ssh[wv][rel][hf][j0],     s1 = ssh[wv][rel][hf][j0 + 1];
      const int s2 = ssh[wv][rel][hf][j0 + 2], s3 = ssh[wv][rel][hf][j0 + 3];
      const float w0 = wsh[wv][rel][hf][j0][hd],     w1 = wsh[wv][rel][hf][j0 + 1][hd];
      const float w2 = wsh[wv][rel][hf][j0 + 2][hd], w3 = wsh[wv][rel][hf][j0 + 3][hd];
      const f32x4 v0 = *(const f32x4*)(hmat + (size_t)s0 * 128 + c0);
      const f32x4 v1 = *(const f32x4*)(hmat + (size_t)s1 * 128 + c0);
      const f32x4 v2 = *(const f32x4*)(hmat + (size_t)s2 * 128 + c0);
      const f32x4 v3 = *(const f32x4*)(hmat + (size_t)s3 * 128 + c0);
      #pragma unroll
      for (int q = 0; q < 4; ++q)
        acc[q] += w0 * v0[q] + w1 * v1[q] + w2 * v2[q] + w3 * v3[q];
    }
  }

  if (!iok) return;
  const f32x4 bbc = *(const f32x4*)(bias_c + c0);
  const f32x4 bbd = *(const f32x4*)(bias_d + c0);
  float* op = out + (size_t)i * 128 + c0;
  const f32x4 cur = *(const f32x4*)op;
  f32x4 res;
  #pragma unroll
  for (int q = 0; q < 4; ++q)
    res[q] = fmaxf(cur[q] + acc[q] + bbc[q] + bbd[q], 0.f);
  *(f32x4*)op = res;
}

// ---------------- output heads ----------------
__global__ __launch_bounds__(256) void k_head(
    const float* __restrict__ h2, const float* __restrict__ Wy, const float* __restrict__ by,
    const float* __restrict__ Wa, const float* __restrict__ ba,
    float* __restrict__ out, int n)
{
  const int r = blockIdx.x * 4 + (threadIdx.x >> 6);
  const int L = threadIdx.x & 63;
  if (r >= n) return;
  const float a = h2[(size_t)r * 128 + L];
  const float b = h2[(size_t)r * 128 + 64 + L];
  float py = a * Wy[L] + b * Wy[64 + L];
  float pa = a * Wa[L] + b * Wa[64 + L];
  #pragma unroll
  for (int o = 32; o; o >>= 1) { py += __shfl_down(py, o); pa += __shfl_down(pa, o); }
  if (L == 0) {
    out[(size_t)r * 2]     = py + by[0];
    out[(size_t)r * 2 + 1] = pa + ba[0];
  }
}

extern "C" void kernel_launch(void* const* d_in, const int* in_sizes, int n_in,
                              void* d_out, int out_size, void* d_ws, size_t ws_size,
                              hipStream_t stream) {
  const int N = in_sizes[0] / 128;
  const int E = in_sizes[2] / 2;
  const int npad = (N + 127) & ~127;

  const float* x       = (const float*)d_in[0];
  const float* pos     = (const float*)d_in[1];
  const int*   ei_chem = (const int*)d_in[2];
  const int*   ei_cond = (const int*)d_in[3];
  const int*   ei_mol  = (const int*)d_in[4];
  const float* bp = (const float*)d_in[6];
  const float* Wy = (const float*)d_in[35];
  const float* by = (const float*)d_in[36];
  const float* Wa = (const float*)d_in[37];
  const float* ba = (const float*)d_in[38];

  char* ws = (char*)d_ws;
  size_t off = 0;
  auto alloc = [&](size_t bytes) -> void* {
    void* p = ws + off; off += (bytes + 255) & ~(size_t)255; return p;
  };
  const size_t HB = (size_t)npad * 128 * sizeof(float);
  float* H0  = (float*)alloc(HB);
  float* ACC = (float*)alloc(HB);
  float* HR  = (float*)alloc(HB);
  int* SRC[3];
  for (int r = 0; r < 3; ++r) SRC[r] = (int*)alloc((size_t)N * MAXDEG * sizeof(int));
  int*   CUR  = (int*)alloc((size_t)3 * N * sizeof(int));
  float* GSUM = (float*)alloc(256);
  float* AS   = (float*)alloc((size_t)npad * 4 * sizeof(float));
  float* AD   = (float*)alloc((size_t)npad * 4 * sizeof(float));
  float* ASd  = (float*)alloc((size_t)npad * 4 * sizeof(float));
  float* ADd  = (float*)alloc((size_t)npad * 4 * sizeof(float));

  // prepped weight images
  PrepArgs pa{};
  const int widx[9] = {5, 7, 11, 15, 19, 21, 25, 29, 33};
  const int fhs[9]  = {0, 64, 64, 32, 0, 64, 64, 32, 0};
  unsigned short *WHI[9], *WLO[9];
  float* CSUM[9];
  for (int s = 0; s < 9; ++s) {
    WHI[s]  = (unsigned short*)alloc(NFRAG * sizeof(unsigned short));
    WLO[s]  = (unsigned short*)alloc(NFRAG * sizeof(unsigned short));
    CSUM[s] = (float*)alloc(144 * sizeof(float));
    pa.W[s] = (const float*)d_in[widx[s]];
    pa.fh[s] = fhs[s];
    pa.as_[s] = fhs[s] ? (const float*)d_in[widx[s] + 1] : nullptr;
    pa.ad_[s] = fhs[s] ? (const float*)d_in[widx[s] + 2] : nullptr;
    pa.hi[s] = WHI[s]; pa.lo[s] = WLO[s]; pa.csum[s] = CSUM[s];
  }

  // 4th big buffer (fused pair-conv path)
  float* HR2 = (float*)alloc(HB);
  const bool fused = (off <= ws_size);
  // 5th big buffer + chem alpha pair (fused 3-GEMM path)
  float* HR3 = (float*)alloc(HB);
  float* ASc = (float*)alloc((size_t)npad * 4 * sizeof(float));
  float* ADc = (float*)alloc((size_t)npad * 4 * sizeof(float));
  const bool fused3 = (off <= ws_size);

  hipMemsetAsync(CUR, 0, (size_t)3 * N * sizeof(int), stream);
  hipMemsetAsync(GSUM, 0, sizeof(float), stream);

  {
    const int nthreads = (3 * E + 3) / 4;
    const int sgrid = (nthreads + 255) / 256;
    k_scatter3<<<sgrid, 256, 0, stream>>>(ei_chem, ei_cond, ei_mol,
                                          CUR, SRC[0], SRC[1], SRC[2],
                                          pos, GSUM, E, N);
  }
  k_prep<<<9, 256, 0, stream>>>(pa);

  const int GG = npad / 128;          // one 128-row block per workgroup
  const float gscale = 0.1f / (float)E;
  const int cgrid = (N + 7) / 8;

  // h0 = x @ Wp + bp
  k_gmm<<<GG, 256, 0, stream>>>(x, WHI[0], WLO[0], CSUM[0], bp, H0,
                                nullptr, nullptr, nullptr, 0.f, N, npad, GF_BIAS);

  auto layer = [&](const float* Hin, float* Acc, int base, int s0) {
    const float* bc = (const float*)d_in[base + 3];
    const float* bd = (const float*)d_in[base + 7];
    const float* bm = (const float*)d_in[base + 11];
    const float* bl = (const float*)d_in[base + 13];
    if (fused3) {
      // one fused GEMM: mol -> HR (+AS/AD, cshift), chem -> HR2 (+ASc/ADc),
      // cond -> HR3 (+ASd/ADd)
      k_gmm3<<<GG, 256, 0, stream>>>(Hin,
                                     WHI[s0+2], WLO[s0+2],
                                     WHI[s0+0], WLO[s0+0],
                                     WHI[s0+1], WLO[s0+1],
                                     CSUM[s0+2], GSUM, gscale,
                                     HR, HR2, HR3,
                                     AS, AD, ASc, ADc, ASd, ADd,
                                     N, npad);
      k_conv<<<cgrid, 256, 0, stream>>>(HR, AS, AD, SRC[2], CUR + 2*N, bm, Acc, 5, 0, N);
      k_gmm<<<GG, 256, 0, stream>>>(Acc, WHI[s0+3], WLO[s0+3], CSUM[s0+3], bl, Acc,
                                    nullptr, nullptr, nullptr, 0.f, N, npad, GF_BIAS);
      k_conv2<<<cgrid, 256, 0, stream>>>(HR2, HR3, ASc, ADc, ASd, ADd,
                                         SRC[0], CUR + 0*N, SRC[1], CUR + 1*N,
                                         bc, bd, Acc, 6, N);
    } else if (fused) {
      k_gmm<<<GG, 256, 0, stream>>>(Hin, WHI[s0+2], WLO[s0+2], CSUM[s0+2], nullptr, HR,
                                    AS, AD, GSUM, gscale, N, npad, GF_CSHIFT | GF_ALPHA);
      k_conv<<<cgrid, 256, 0, stream>>>(HR, AS, AD, SRC[2], CUR + 2*N, bm, Acc, 5, 0, N);
      k_gmm<<<GG, 256, 0, stream>>>(Acc, WHI[s0+3], WLO[s0+3], CSUM[s0+3], bl, Acc,
                                    nullptr, nullptr, nullptr, 0.f, N, npad, GF_BIAS);
      k_gmm<<<GG, 256, 0, stream>>>(Hin, WHI[s0+0], WLO[s0+0], CSUM[s0+0], nullptr, HR,
                                    AS, AD, nullptr, 0.f, N, npad, GF_ALPHA);
      k_gmm<<<GG, 256, 0, stream>>>(Hin, WHI[s0+1], WLO[s0+1], CSUM[s0+1], nullptr, HR2,
                                    ASd, ADd, nullptr, 0.f, N, npad, GF_ALPHA);
      k_conv2<<<cgrid, 256, 0, stream>>>(HR, HR2, AS, AD, ASd, ADd,
                                         SRC[0], CUR + 0*N, SRC[1], CUR + 1*N,
                                         bc, bd, Acc, 6, N);
    } else {
      k_gmm<<<GG, 256, 0, stream>>>(Hin, WHI[s0+2], WLO[s0+2], CSUM[s0+2], nullptr, HR,
                                    AS, AD, GSUM, gscale, N, npad, GF_CSHIFT | GF_ALPHA);
      k_conv<<<cgrid, 256, 0, stream>>>(HR, AS, AD, SRC[2], CUR + 2*N, bm, Acc, 5, 0, N);
      k_gmm<<<GG, 256, 0, stream>>>(Acc, WHI[s0+3], WLO[s0+3], CSUM[s0+3], bl, Acc,
                                    nullptr, nullptr, nullptr, 0.f, N, npad, GF_BIAS);
      k_gmm<<<GG, 256, 0, stream>>>(Hin, WHI[s0+0], WLO[s0+0], CSUM[s0+0], nullptr, HR,
                                    AS, AD, nullptr, 0.f, N, npad, GF_ALPHA);
      k_conv<<<cgrid, 256, 0, stream>>>(HR, AS, AD, SRC[0], CUR + 0*N, bc, Acc, 6, 1, N);
      k_gmm<<<GG, 256, 0, stream>>>(Hin, WHI[s0+1], WLO[s0+1], CSUM[s0+1], nullptr, HR,
                                    AS, AD, nullptr, 0.f, N, npad, GF_ALPHA);
      k_conv<<<cgrid, 256, 0, stream>>>(HR, AS, AD, SRC[1], CUR + 1*N, bd, Acc, 6, 2, N);
    }
  };

  layer(H0, ACC, 7, 1);    // h1 in ACC
  layer(ACC, H0, 21, 5);   // h2 in H0

  k_head<<<(N + 3) / 4, 256, 0, stream>>>(H0, Wy, by, Wa, ba, (float*)d_out, N);
}

// Round 9
// 761.364 us; speedup vs baseline: 1.2642x; 1.2642x over previous
//
#include <hip/hip_runtime.h>
#include <math.h>

typedef short short8 __attribute__((ext_vector_type(8)));
typedef float f32x4 __attribute__((ext_vector_type(4)));
typedef unsigned short us4 __attribute__((ext_vector_type(4)));

#define MAXDEG 32
#define GF_BIAS   1
#define GF_CSHIFT 2
#define GF_ALPHA  4
#define GF_BF16   8
#define NFRAG 18432   // 9 nt-tiles * 4 kt * 64 lanes * 8 bf16

__device__ __forceinline__ unsigned short f2bf(float f) {  // RNE f32->bf16
  unsigned u = __float_as_uint(f);
  u += 0x7FFF + ((u >> 16) & 1);
  return (unsigned short)(u >> 16);
}
__device__ __forceinline__ float bf2f(unsigned short s) { return __uint_as_float(((unsigned)s) << 16); }
__device__ __forceinline__ float lrelu(float v) { return v > 0.f ? v : 0.2f * v; }

// ---------------- CSR slot-scatter (3 relations) + fused geo reduce, 4-way ILP ------
__global__ __launch_bounds__(256) void k_scatter3(
    const int* __restrict__ ei0, const int* __restrict__ ei1, const int* __restrict__ ei2,
    int* __restrict__ cur,
    int* __restrict__ s0, int* __restrict__ s1, int* __restrict__ s2,
    const float* __restrict__ pos, float* __restrict__ gsum, int E, int N) {
  __shared__ float part[4];
  const int T4 = gridDim.x * 256;
  const int t = blockIdx.x * 256 + threadIdx.x;
  float d = 0.f;
  #pragma unroll
  for (int k = 0; k < 4; ++k) {
    const int idx = t + k * T4;
    if (idx >= 3 * E) continue;
    int rel, e;
    if (idx < E)          { rel = 0; e = idx; }
    else if (idx < 2 * E) { rel = 1; e = idx - E; }
    else                  { rel = 2; e = idx - 2 * E; }
    const int* ei = (rel == 0) ? ei0 : (rel == 1) ? ei1 : ei2;
    int* srcs     = (rel == 0) ? s0  : (rel == 1) ? s1  : s2;
    const int r = ei[e];
    const int c = ei[E + e];
    const int slot = atomicAdd(&cur[rel * N + c], 1);
    if (slot < MAXDEG) srcs[(size_t)c * MAXDEG + slot] = r;
    if (rel == 2) {
      const float dx = pos[3*r]   - pos[3*c];
      const float dy = pos[3*r+1] - pos[3*c+1];
      const float dz = pos[3*r+2] - pos[3*c+2];
      d += sqrtf(dx*dx + dy*dy + dz*dz);
    }
  }
  #pragma unroll
  for (int o = 32; o; o >>= 1) d += __shfl_down(d, o);
  if ((threadIdx.x & 63) == 0) part[threadIdx.x >> 6] = d;
  __syncthreads();
  if (threadIdx.x == 0) {
    const float s = part[0] + part[1] + part[2] + part[3];
    if (s != 0.f) atomicAdd(gsum, s);
  }
}

// ---------------- weight prep: bf16 hi/lo fragment images + alpha cols + colsums ----
struct PrepArgs {
  const float* W[9];
  const float* as_[9];
  const float* ad_[9];
  unsigned short* hi[9];
  unsigned short* lo[9];
  float* csum[9];
  int fh[9];   // 0 = no alpha cols
};

__global__ __launch_bounds__(256) void k_prep(PrepArgs p) {
  const int s = blockIdx.x;
  const int t = threadIdx.x;
  const float* W = p.W[s];
  const int fh = p.fh[s];
  __shared__ float Ws[128 * 129];
  __shared__ float alpha[128 * 8];
  {
    const f32x4* src = (const f32x4*)W;
    for (int i = t; i < 4096; i += 256) {     // 16384 floats, coalesced
      const f32x4 v = src[i];
      const int row = i >> 5;
      const int col = (i & 31) * 4;
      float* dst = &Ws[row * 129 + col];
      dst[0] = v[0]; dst[1] = v[1]; dst[2] = v[2]; dst[3] = v[3];
    }
  }
  __syncthreads();
  if (t < 128) {
    #pragma unroll
    for (int a = 0; a < 8; ++a) alpha[t * 8 + a] = 0.f;
    if (fh) {
      const int nh = 128 / fh;
      for (int h = 0; h < nh; ++h) {
        float s1 = 0.f, s2 = 0.f;
        for (int c = 0; c < fh; ++c) {
          const float w = Ws[t * 129 + h * fh + c];
          s1 += w * p.as_[s][h * fh + c];
          s2 += w * p.ad_[s][h * fh + c];
        }
        alpha[t * 8 + h] = s1;
        alpha[t * 8 + 4 + h] = s2;
      }
    }
  }
  __syncthreads();
  for (int idx = t; idx < NFRAG; idx += 256) {
    const int j = idx & 7, lane = (idx >> 3) & 63, kt = (idx >> 9) & 3, nt = idx >> 11;
    const int k = kt * 32 + (lane >> 4) * 8 + j;
    const int col = nt * 16 + (lane & 15);
    float w;
    if (col < 128) w = Ws[k * 129 + col];
    else if (col < 136) w = alpha[k * 8 + (col - 128)];
    else w = 0.f;
    const unsigned short h = f2bf(w);
    p.hi[s][idx] = h;
    p.lo[s][idx] = f2bf(w - bf2f(h));
  }
  if (t < 136) {
    float cs = 0.f;
    if (t < 128) for (int k = 0; k < 128; ++k) cs += Ws[k * 129 + t];
    else         for (int k = 0; k < 128; ++k) cs += alpha[k * 8 + (t - 128)];
    p.csum[s][t] = cs;
  }
}

// ---------------- split-bf16 MFMA GEMM: C[n,128] = A[n,128] @ W[128,128] -------------
// LDS-staged weights (proven best: R8's L2-direct variant regressed 19us/GEMM).
// GF_BF16: write C as bf16 (for gather-only consumers -> halves conv gather traffic).
__global__ __launch_bounds__(256, 2) void k_gmm(
    const float* __restrict__ A, const unsigned short* __restrict__ Whi,
    const unsigned short* __restrict__ Wlo, const float* __restrict__ csum,
    const float* __restrict__ bias, float* __restrict__ C,
    float* __restrict__ aS, float* __restrict__ aD,
    const float* __restrict__ gsum, float gscale,
    int n, int npad, int flags)
{
  __shared__ unsigned short shi[NFRAG];
  __shared__ unsigned short slo[NFRAG];
  {
    const f32x4* srch = (const f32x4*)Whi;
    const f32x4* srcl = (const f32x4*)Wlo;
    f32x4* dsth = (f32x4*)shi;
    f32x4* dstl = (f32x4*)slo;
    for (int i = threadIdx.x; i < NFRAG / 8; i += 256) { dsth[i] = srch[i]; dstl[i] = srcl[i]; }
  }
  __syncthreads();

  const int wave = threadIdx.x >> 6, lane = threadIdx.x & 63;
  const int m = lane & 15, kq = lane >> 4;
  const float cb = (flags & GF_CSHIFT) ? gscale * gsum[0] : 0.f;

  for (int rb = blockIdx.x * 128; rb < npad; rb += gridDim.x * 128) {
    const int rw = rb + wave * 32;
    short8 ah[2][4], al[2][4];
    #pragma unroll
    for (int sub = 0; sub < 2; ++sub) {
      const int row = rw + sub * 16 + m;
      const bool ok = row < n;
      const float* ap = A + (size_t)row * 128 + kq * 8;
      #pragma unroll
      for (int kt = 0; kt < 4; ++kt) {
        f32x4 x0 = {0.f, 0.f, 0.f, 0.f}, x1 = {0.f, 0.f, 0.f, 0.f};
        if (ok) { x0 = *(const f32x4*)(ap + kt * 32); x1 = *(const f32x4*)(ap + kt * 32 + 4); }
        #pragma unroll
        for (int j = 0; j < 4; ++j) {
          unsigned short h0 = f2bf(x0[j]);
          ah[sub][kt][j] = (short)h0;
          al[sub][kt][j] = (short)f2bf(x0[j] - bf2f(h0));
          unsigned short h1 = f2bf(x1[j]);
          ah[sub][kt][4 + j] = (short)h1;
          al[sub][kt][4 + j] = (short)f2bf(x1[j] - bf2f(h1));
        }
      }
    }
    f32x4 acc[2][9];
    #pragma unroll
    for (int sub = 0; sub < 2; ++sub)
      #pragma unroll
      for (int nt = 0; nt < 9; ++nt) acc[sub][nt] = f32x4{0.f, 0.f, 0.f, 0.f};

    #pragma unroll
    for (int nt = 0; nt < 9; ++nt) {
      #pragma unroll
      for (int kt = 0; kt < 4; ++kt) {
        const int fo = ((nt * 4 + kt) * 64 + lane) * 8;
        const short8 bh = *(const short8*)&shi[fo];
        const short8 bl = *(const short8*)&slo[fo];
        #pragma unroll
        for (int sub = 0; sub < 2; ++sub) {
          acc[sub][nt] = __builtin_amdgcn_mfma_f32_16x16x32_bf16(ah[sub][kt], bh, acc[sub][nt], 0, 0, 0);
          acc[sub][nt] = __builtin_amdgcn_mfma_f32_16x16x32_bf16(al[sub][kt], bh, acc[sub][nt], 0, 0, 0);
          acc[sub][nt] = __builtin_amdgcn_mfma_f32_16x16x32_bf16(ah[sub][kt], bl, acc[sub][nt], 0, 0, 0);
        }
      }
    }
    // epilogue: C/D layout col = lane&15, row = (lane>>4)*4 + r
    #pragma unroll
    for (int sub = 0; sub < 2; ++sub) {
      const int rbase = rw + sub * 16 + kq * 4;
      #pragma unroll
      for (int nt = 0; nt < 8; ++nt) {
        const int col = nt * 16 + m;
        const float cs = (flags & GF_CSHIFT) ? cb * csum[col] : 0.f;
        const float bb = (flags & GF_BIAS) ? bias[col] : 0.f;
        if (flags & GF_BF16) {
          unsigned short* Cb = (unsigned short*)C;
          #pragma unroll
          for (int r = 0; r < 4; ++r)
            Cb[(size_t)(rbase + r) * 128 + col] = f2bf(acc[sub][nt][r] + cs);
        } else {
          #pragma unroll
          for (int r = 0; r < 4; ++r)
            C[(size_t)(rbase + r) * 128 + col] = acc[sub][nt][r] + cs + bb;
        }
      }
      if ((flags & GF_ALPHA) && m < 8) {
        const float cs = (flags & GF_CSHIFT) ? cb * csum[128 + m] : 0.f;
        #pragma unroll
        for (int r = 0; r < 4; ++r) {
          const float v = acc[sub][8][r] + cs;
          const int row = rbase + r;
          if (m < 4) aS[(size_t)row * 4 + m] = v;
          else       aD[(size_t)row * 4 + (m - 4)] = v;
        }
      }
    }
  }
}

// ---------------- GAT conv (bf16 h rows): 2 dst nodes/wave, 32 lanes each ----------
// mode: 0 = write, 1 = accumulate, 2 = accumulate + relu
__global__ __launch_bounds__(256) void k_conv(
    const unsigned short* __restrict__ hb, const float* __restrict__ aS,
    const float* __restrict__ aD,
    const int* __restrict__ srcs, const int* __restrict__ cnt,
    const float* __restrict__ bias, float* __restrict__ out,
    int fh_shift, int mode, int n)
{
  __shared__ int   ssh[4][2][32];
  __shared__ float wsh[4][2][32][4];
  const int wv = threadIdx.x >> 6;
  const int lane = threadIdx.x & 63;
  const int hf = lane >> 5;
  const int l  = lane & 31;
  const int i = blockIdx.x * 8 + wv * 2 + hf;
  const bool iok = i < n;
  const int ipad = iok ? i : 0;
  const int c0 = l * 4;
  const int hd = c0 >> fh_shift;

  int deg = 0;
  if (iok) { deg = cnt[i]; if (deg > MAXDEG) deg = MAXDEG; }
  const int* sp = srcs + (size_t)ipad * MAXDEG;

  const bool valid = l < deg;
  int s = ipad;
  if (valid) s = sp[l];

  f32x4 ad4 = f32x4{0.f, 0.f, 0.f, 0.f}, asi = f32x4{0.f, 0.f, 0.f, 0.f};
  if (iok) {
    ad4 = *(const f32x4*)(aD + (size_t)i * 4);
    asi = *(const f32x4*)(aS + (size_t)i * 4);
  }
  f32x4 as4 = f32x4{0.f, 0.f, 0.f, 0.f};
  if (valid) as4 = *(const f32x4*)(aS + (size_t)s * 4);

  f32x4 e, eself;
  #pragma unroll
  for (int hh = 0; hh < 4; ++hh) {
    e[hh] = lrelu(as4[hh] + ad4[hh]);
    eself[hh] = lrelu(asi[hh] + ad4[hh]);
  }

  f32x4 mx;
  #pragma unroll
  for (int hh = 0; hh < 4; ++hh) mx[hh] = valid ? e[hh] : -1e30f;
  #pragma unroll
  for (int o = 16; o; o >>= 1) {
    #pragma unroll
    for (int hh = 0; hh < 4; ++hh) mx[hh] = fmaxf(mx[hh], __shfl_xor(mx[hh], o, 32));
  }
  #pragma unroll
  for (int hh = 0; hh < 4; ++hh) mx[hh] = fmaxf(mx[hh], eself[hh]);

  f32x4 w, z;
  #pragma unroll
  for (int hh = 0; hh < 4; ++hh) { w[hh] = valid ? __expf(e[hh] - mx[hh]) : 0.f; z[hh] = w[hh]; }
  #pragma unroll
  for (int o = 16; o; o >>= 1) {
    #pragma unroll
    for (int hh = 0; hh < 4; ++hh) z[hh] += __shfl_xor(z[hh], o, 32);
  }
  f32x4 wsf;
  #pragma unroll
  for (int hh = 0; hh < 4; ++hh) { wsf[hh] = __expf(eself[hh] - mx[hh]); z[hh] += wsf[hh]; }

  int dtot = (deg + 3) & ~3;
  const int dmax = max(dtot, __shfl_xor(dtot, 32));
  if (l < dmax) {
    ssh[wv][hf][l] = valid ? s : ipad;
    f32x4 wst = f32x4{0.f, 0.f, 0.f, 0.f};
    if (valid) wst = w;
    *(f32x4*)wsh[wv][hf][l] = wst;
  }

  f32x4 acc = f32x4{0.f, 0.f, 0.f, 0.f};
  {
    us4 u = {0, 0, 0, 0};
    if (iok) u = *(const us4*)(hb + (size_t)i * 128 + c0);
    const float ws = wsf[hd];
    #pragma unroll
    for (int q = 0; q < 4; ++q) acc[q] = ws * bf2f(u[q]);
  }
  for (int j0 = 0; j0 < dmax; j0 += 4) {
    const int s0 = ssh[wv][hf][j0],     s1 = ssh[wv][hf][j0 + 1];
    const int s2 = ssh[wv][hf][j0 + 2], s3 = ssh[wv][hf][j0 + 3];
    const float w0 = wsh[wv][hf][j0][hd],     w1 = wsh[wv][hf][j0 + 1][hd];
    const float w2 = wsh[wv][hf][j0 + 2][hd], w3 = wsh[wv][hf][j0 + 3][hd];
    const us4 u0 = *(const us4*)(hb + (size_t)s0 * 128 + c0);
    const us4 u1 = *(const us4*)(hb + (size_t)s1 * 128 + c0);
    const us4 u2 = *(const us4*)(hb + (size_t)s2 * 128 + c0);
    const us4 u3 = *(const us4*)(hb + (size_t)s3 * 128 + c0);
    #pragma unroll
    for (int q = 0; q < 4; ++q)
      acc[q] += w0 * bf2f(u0[q]) + w1 * bf2f(u1[q]) + w2 * bf2f(u2[q]) + w3 * bf2f(u3[q]);
  }

  if (!iok) return;
  const float inv = 1.f / (z[hd] + 1e-16f);
  const f32x4 bb = *(const f32x4*)(bias + c0);
  float* op = out + (size_t)i * 128 + c0;
  f32x4 res;
  #pragma unroll
  for (int q = 0; q < 4; ++q) res[q] = acc[q] * inv + bb[q];
  if (mode == 0) { *(f32x4*)op = res; }
  else {
    f32x4 cur = *(const f32x4*)op;
    #pragma unroll
    for (int q = 0; q < 4; ++q) {
      float r = cur[q] + res[q];
      if (mode == 2) r = fmaxf(r, 0.f);
      res[q] = r;
    }
    *(f32x4*)op = res;
  }
}

// ---------------- fused 2-relation GAT conv (bf16 h): out = relu(out + c + d) ------
__global__ __launch_bounds__(256) void k_conv2(
    const unsigned short* __restrict__ hcp, const unsigned short* __restrict__ hdp,
    const float* __restrict__ aSc, const float* __restrict__ aDc,
    const float* __restrict__ aSd, const float* __restrict__ aDd,
    const int* __restrict__ srcs_c, const int* __restrict__ cnt_c,
    const int* __restrict__ srcs_d, const int* __restrict__ cnt_d,
    const float* __restrict__ bias_c, const float* __restrict__ bias_d,
    float* __restrict__ out, int fh_shift, int n)
{
  __shared__ int   ssh[4][2][2][32];        // [wave][rel][half][slot]
  __shared__ float wsh[4][2][2][32][4];
  const int wv = threadIdx.x >> 6;
  const int lane = threadIdx.x & 63;
  const int hf = lane >> 5;
  const int l  = lane & 31;
  const int i = blockIdx.x * 8 + wv * 2 + hf;
  const bool iok = i < n;
  const int ipad = iok ? i : 0;
  const int c0 = l * 4;
  const int hd = c0 >> fh_shift;

  const unsigned short* hA[2] = {hcp, hdp};
  const float* aSA[2]  = {aSc, aSd};
  const float* aDA[2]  = {aDc, aDd};
  const int*   spA[2]  = {srcs_c, srcs_d};
  const int*   cntA[2] = {cnt_c, cnt_d};

  f32x4 acc = f32x4{0.f, 0.f, 0.f, 0.f};

  #pragma unroll
  for (int rel = 0; rel < 2; ++rel) {
    int deg = 0;
    if (iok) { deg = cntA[rel][i]; if (deg > MAXDEG) deg = MAXDEG; }
    const int* sp = spA[rel] + (size_t)ipad * MAXDEG;

    const bool valid = l < deg;
    int s = ipad;
    if (valid) s = sp[l];

    f32x4 ad4 = f32x4{0.f, 0.f, 0.f, 0.f}, asi = f32x4{0.f, 0.f, 0.f, 0.f};
    if (iok) {
      ad4 = *(const f32x4*)(aDA[rel] + (size_t)i * 4);
      asi = *(const f32x4*)(aSA[rel] + (size_t)i * 4);
    }
    f32x4 as4 = f32x4{0.f, 0.f, 0.f, 0.f};
    if (valid) as4 = *(const f32x4*)(aSA[rel] + (size_t)s * 4);

    f32x4 e, eself;
    #pragma unroll
    for (int hh = 0; hh < 4; ++hh) {
      e[hh] = lrelu(as4[hh] + ad4[hh]);
      eself[hh] = lrelu(asi[hh] + ad4[hh]);
    }

    f32x4 mx;
    #pragma unroll
    for (int hh = 0; hh < 4; ++hh) mx[hh] = valid ? e[hh] : -1e30f;
    #pragma unroll
    for (int o = 16; o; o >>= 1) {
      #pragma unroll
      for (int hh = 0; hh < 4; ++hh) mx[hh] = fmaxf(mx[hh], __shfl_xor(mx[hh], o, 32));
    }
    #pragma unroll
    for (int hh = 0; hh < 4; ++hh) mx[hh] = fmaxf(mx[hh], eself[hh]);

    f32x4 w, z;
    #pragma unroll
    for (int hh = 0; hh < 4; ++hh) { w[hh] = valid ? __expf(e[hh] - mx[hh]) : 0.f; z[hh] = w[hh]; }
    #pragma unroll
    for (int o = 16; o; o >>= 1) {
      #pragma unroll
      for (int hh = 0; hh < 4; ++hh) z[hh] += __shfl_xor(z[hh], o, 32);
    }
    f32x4 wsf, inv;
    #pragma unroll
    for (int hh = 0; hh < 4; ++hh) {
      wsf[hh] = __expf(eself[hh] - mx[hh]);
      z[hh] += wsf[hh];
      inv[hh] = 1.f / (z[hh] + 1e-16f);
    }

    int dtot = (deg + 3) & ~3;
    const int dmax = max(dtot, __shfl_xor(dtot, 32));
    if (l < dmax) {
      ssh[wv][rel][hf][l] = valid ? s : ipad;
      f32x4 wst = f32x4{0.f, 0.f, 0.f, 0.f};
      if (valid) {
        #pragma unroll
        for (int hh = 0; hh < 4; ++hh) wst[hh] = w[hh] * inv[hh];
      }
      *(f32x4*)wsh[wv][rel][hf][l] = wst;
    }

    const unsigned short* hmat = hA[rel];
    // self row (normalized weight)
    {
      us4 u = {0, 0, 0, 0};
      if (iok) u = *(const us4*)(hmat + (size_t)i * 128 + c0);
      const float ws = wsf[hd] * inv[hd];
      #pragma unroll
      for (int q = 0; q < 4; ++q) acc[q] += ws * bf2f(u[q]);
    }
    for (int j0 = 0; j0 < dmax; j0 += 4) {
      const int s0 = ssh[wv][rel][hf][j0],     s1 = ssh[wv][rel][hf][j0 + 1];
      const int s2 = ssh[wv][rel][hf][j0 + 2], s3 = ssh[wv][rel][hf][j0 + 3];
      const float w0 = wsh[wv][rel][hf][j0][hd],     w1 = wsh[wv][rel][hf][j0 + 1][hd];
      const float w2 = wsh[wv][rel][hf][j0 + 2][hd], w3 = wsh[wv][rel][hf][j0 + 3][hd];
      const us4 u0 = *(const us4*)(hmat + (size_t)s0 * 128 + c0);
      const us4 u1 = *(const us4*)(hmat + (size_t)s1 * 128 + c0);
      const us4 u2 = *(const us4*)(hmat + (size_t)s2 * 128 + c0);
      const us4 u3 = *(const us4*)(hmat + (size_t)s3 * 128 + c0);
      #pragma unroll
      for (int q = 0; q < 4; ++q)
        acc[q] += w0 * bf2f(u0[q]) + w1 * bf2f(u1[q]) + w2 * bf2f(u2[q]) + w3 * bf2f(u3[q]);
    }
  }

  if (!iok) return;
  const f32x4 bbc = *(const f32x4*)(bias_c + c0);
  const f32x4 bbd = *(const f32x4*)(bias_d + c0);
  float* op = out + (size_t)i * 128 + c0;
  const f32x4 cur = *(const f32x4*)op;
  f32x4 res;
  #pragma unroll
  for (int q = 0; q < 4; ++q)
    res[q] = fmaxf(cur[q] + acc[q] + bbc[q] + bbd[q], 0.f);
  *(f32x4*)op = res;
}

// ---------------- output heads ----------------
__global__ __launch_bounds__(256) void k_head(
    const float* __restrict__ h2, const float* __restrict__ Wy, const float* __restrict__ by,
    const float* __restrict__ Wa, const float* __restrict__ ba,
    float* __restrict__ out, int n)
{
  const int r = blockIdx.x * 4 + (threadIdx.x >> 6);
  const int L = threadIdx.x & 63;
  if (r >= n) return;
  const float a = h2[(size_t)r * 128 + L];
  const float b = h2[(size_t)r * 128 + 64 + L];
  float py = a * Wy[L] + b * Wy[64 + L];
  float pa = a * Wa[L] + b * Wa[64 + L];
  #pragma unroll
  for (int o = 32; o; o >>= 1) { py += __shfl_down(py, o); pa += __shfl_down(pa, o); }
  if (L == 0) {
    out[(size_t)r * 2]     = py + by[0];
    out[(size_t)r * 2 + 1] = pa + ba[0];
  }
}

extern "C" void kernel_launch(void* const* d_in, const int* in_sizes, int n_in,
                              void* d_out, int out_size, void* d_ws, size_t ws_size,
                              hipStream_t stream) {
  const int N = in_sizes[0] / 128;
  const int E = in_sizes[2] / 2;
  const int npad = (N + 127) & ~127;

  const float* x       = (const float*)d_in[0];
  const float* pos     = (const float*)d_in[1];
  const int*   ei_chem = (const int*)d_in[2];
  const int*   ei_cond = (const int*)d_in[3];
  const int*   ei_mol  = (const int*)d_in[4];
  const float* bp = (const float*)d_in[6];
  const float* Wy = (const float*)d_in[35];
  const float* by = (const float*)d_in[36];
  const float* Wa = (const float*)d_in[37];
  const float* ba = (const float*)d_in[38];

  char* ws = (char*)d_ws;
  size_t off = 0;
  auto alloc = [&](size_t bytes) -> void* {
    void* p = ws + off; off += (bytes + 255) & ~(size_t)255; return p;
  };
  const size_t HB = (size_t)npad * 128 * sizeof(float);
  const size_t HBH = (size_t)npad * 128 * sizeof(unsigned short);
  float* H0  = (float*)alloc(HB);
  float* ACC = (float*)alloc(HB);
  unsigned short* HRb  = (unsigned short*)alloc(HBH);
  unsigned short* HRb2 = (unsigned short*)alloc(HBH);
  int* SRC[3];
  for (int r = 0; r < 3; ++r) SRC[r] = (int*)alloc((size_t)N * MAXDEG * sizeof(int));
  int*   CUR  = (int*)alloc((size_t)3 * N * sizeof(int));
  float* GSUM = (float*)alloc(256);
  float* AS   = (float*)alloc((size_t)npad * 4 * sizeof(float));
  float* AD   = (float*)alloc((size_t)npad * 4 * sizeof(float));
  float* ASd  = (float*)alloc((size_t)npad * 4 * sizeof(float));
  float* ADd  = (float*)alloc((size_t)npad * 4 * sizeof(float));

  // prepped weight images
  PrepArgs pa{};
  const int widx[9] = {5, 7, 11, 15, 19, 21, 25, 29, 33};
  const int fhs[9]  = {0, 64, 64, 32, 0, 64, 64, 32, 0};
  unsigned short *WHI[9], *WLO[9];
  float* CSUM[9];
  for (int s = 0; s < 9; ++s) {
    WHI[s]  = (unsigned short*)alloc(NFRAG * sizeof(unsigned short));
    WLO[s]  = (unsigned short*)alloc(NFRAG * sizeof(unsigned short));
    CSUM[s] = (float*)alloc(144 * sizeof(float));
    pa.W[s] = (const float*)d_in[widx[s]];
    pa.fh[s] = fhs[s];
    pa.as_[s] = fhs[s] ? (const float*)d_in[widx[s] + 1] : nullptr;
    pa.ad_[s] = fhs[s] ? (const float*)d_in[widx[s] + 2] : nullptr;
    pa.hi[s] = WHI[s]; pa.lo[s] = WLO[s]; pa.csum[s] = CSUM[s];
  }

  hipMemsetAsync(CUR, 0, (size_t)3 * N * sizeof(int), stream);
  hipMemsetAsync(GSUM, 0, sizeof(float), stream);

  {
    const int nthreads = (3 * E + 3) / 4;
    const int sgrid = (nthreads + 255) / 256;
    k_scatter3<<<sgrid, 256, 0, stream>>>(ei_chem, ei_cond, ei_mol,
                                          CUR, SRC[0], SRC[1], SRC[2],
                                          pos, GSUM, E, N);
  }
  k_prep<<<9, 256, 0, stream>>>(pa);

  const int GG = 512;
  const float gscale = 0.1f / (float)E;
  const int cgrid = (N + 7) / 8;

  // h0 = x @ Wp + bp
  k_gmm<<<GG, 256, 0, stream>>>(x, WHI[0], WLO[0], CSUM[0], bp, H0,
                                nullptr, nullptr, nullptr, 0.f, N, npad, GF_BIAS);

  auto layer = [&](const float* Hin, float* Acc, int base, int s0) {
    const float* bc = (const float*)d_in[base + 3];
    const float* bd = (const float*)d_in[base + 7];
    const float* bm = (const float*)d_in[base + 11];
    const float* bl = (const float*)d_in[base + 13];
    // EQGAT (mol, heads=4): GEMM(bf16 out) + alpha + cshift; conv writes Acc; Wl in-place
    k_gmm<<<GG, 256, 0, stream>>>(Hin, WHI[s0+2], WLO[s0+2], CSUM[s0+2], nullptr,
                                  (float*)HRb, AS, AD, GSUM, gscale, N, npad,
                                  GF_CSHIFT | GF_ALPHA | GF_BF16);
    k_conv<<<cgrid, 256, 0, stream>>>(HRb, AS, AD, SRC[2], CUR + 2*N, bm, Acc, 5, 0, N);
    k_gmm<<<GG, 256, 0, stream>>>(Acc, WHI[s0+3], WLO[s0+3], CSUM[s0+3], bl, Acc,
                                  nullptr, nullptr, nullptr, 0.f, N, npad, GF_BIAS);
    // chem -> HRb (+AS/AD), cond -> HRb2 (+ASd/ADd), fused conv with relu
    k_gmm<<<GG, 256, 0, stream>>>(Hin, WHI[s0+0], WLO[s0+0], CSUM[s0+0], nullptr,
                                  (float*)HRb, AS, AD, nullptr, 0.f, N, npad,
                                  GF_ALPHA | GF_BF16);
    k_gmm<<<GG, 256, 0, stream>>>(Hin, WHI[s0+1], WLO[s0+1], CSUM[s0+1], nullptr,
                                  (float*)HRb2, ASd, ADd, nullptr, 0.f, N, npad,
                                  GF_ALPHA | GF_BF16);
    k_conv2<<<cgrid, 256, 0, stream>>>(HRb, HRb2, AS, AD, ASd, ADd,
                                       SRC[0], CUR + 0*N, SRC[1], CUR + 1*N,
                                       bc, bd, Acc, 6, N);
  };

  layer(H0, ACC, 7, 1);    // h1 in ACC
  layer(ACC, H0, 21, 5);   // h2 in H0

  k_head<<<(N + 3) / 4, 256, 0, stream>>>(H0, Wy, by, Wa, ba, (float*)d_out, N);
}